// Round 19
// baseline (529.110 us; speedup 1.0000x reference)
//
#include <hip/hip_runtime.h>

#define HID  64
#define SEQT 1024
#define NB   4

typedef _Float16 h8 __attribute__((ext_vector_type(8)));
typedef float    f4 __attribute__((ext_vector_type(4)));
typedef float    v2f __attribute__((ext_vector_type(2)));

__device__ __forceinline__ float rcpf(float x){ return __builtin_amdgcn_rcpf(x); }
__device__ __forceinline__ float sigm(float x){ return rcpf(1.0f + __expf(-x)); }
__device__ __forceinline__ float tanh_fast(float x){
    // 1 - 2/(e^{2x}+1); correct saturation at +-inf
    return 1.0f - 2.0f * rcpf(__expf(2.0f * x) + 1.0f);
}

#define MFMA16(A,B,C) __builtin_amdgcn_mfma_f32_16x16x32_f16((A),(B),(C),0,0,0)

// round 8 fp32 values to f16 (1-term weights)
__device__ __forceinline__ h8 cvt8(const float* __restrict__ p) {
    float4 u = *(const float4*)p;
    float4 v = *(const float4*)(p + 4);
    h8 r;
    r[0] = (_Float16)u.x; r[1] = (_Float16)u.y;
    r[2] = (_Float16)u.z; r[3] = (_Float16)u.w;
    r[4] = (_Float16)v.x; r[5] = (_Float16)v.y;
    r[6] = (_Float16)v.z; r[7] = (_Float16)v.w;
    return r;
}

// v18 wave-specialized skeleton + three refinements:
//  1. 12/12 MFMA phase balance: A = L0(8) + L1h1 tiles{0,1}(4);
//     B = L1h1 tiles{2,3}(4) + L1h2 all(8). Partials ride registers A->B.
//  2. Unit-major G via W-row permutation (write-side only): tile tt A-row
//     rho <- W row 64*(rho&3) + 16j + 4tt + (rho>>2). Then lane (g4,r16)'s
//     acc[reg] = gate reg of unit u=16j+4tt+g4, batch r16 -> G stored as
//     [batch][unit*4+gate] f32; the cell wave reads its unit's 4 gates with
//     ONE ds_read_b128 (was 4x ds_read_b32), conflict-free stride pattern.
//  3. Cell waves run at s_setprio(1) persistently (they own the serial
//     recurrence chain); MFMA waves keep cluster-scoped setprio.
// Roles: waves 0-3 pure MFMA (wave j: units 16j..16j+15, all gates);
// waves 4-7 pure cell (wave 4+b: batch b; cell1(t-2) in A, cell0(t) in B).
// Dataflow identical to v18 (G0: A->B; G1: B->A+1; h parity dbuf; 2 bar).
// 1-term f16 weights + f16-exact h state (absmax 1.2207e-4, 3 rounds stable).
__global__ __launch_bounds__(512, 2)
void lstm2_v19(const float* __restrict__ x,
               const float* __restrict__ W_ih0, const float* __restrict__ W_hh0,
               const float* __restrict__ b_ih0, const float* __restrict__ b_hh0,
               const float* __restrict__ W_ih1, const float* __restrict__ W_hh1,
               const float* __restrict__ b_ih1, const float* __restrict__ b_hh1,
               const float* __restrict__ fc1_w, const float* __restrict__ fc1_b,
               const float* __restrict__ fc2_w, const float* __restrict__ fc2_b,
               float* __restrict__ out, int nblk)
{
    const int blk = blockIdx.x;
    if (blk >= nblk) return;
    const int tid = threadIdx.x;
    const int w   = tid >> 6;          // wave 0..7
    const int l   = tid & 63;          // lane
    const int r16 = l & 15;            // A row in tile / D col (batch)
    const int g4  = l >> 4;            // k-subgroup / D row group
    const int cc  = r16 & 3;           // batch col for B-frag broadcast
    const bool isCell = (w >= 4);
    const int cb  = w & 3;             // cell batch (cell waves)
    const int B0  = blk * NB;

    // ---------------- LDS ----------------
    __shared__ __align__(16) _Float16 h1f[2][NB][80];   // f16-exact h1
    __shared__ __align__(16) _Float16 h2f16[2][NB][80]; // f16-exact h2
    __shared__ __align__(16) float G0[NB][260];         // [batch][unit*4+gate]
    __shared__ __align__(16) float G1[NB][260];
    __shared__ __align__(16) float h2fin[NB][64];

    // ------ A-fragments (MFMA waves), ROW-PERMUTED for unit-major D --------
    // tile tt, A-row rho <- W row 64*(rho&3) + 16j + 4tt + (rho>>2)
    h8 a0[4][2];   // [tile][ks]  W_hh0
    h8 a1[4][4];   // [tile][ks]  ks 0,1: W_ih1 ; ks 2,3: W_hh1
    if (!isCell) {
        #pragma unroll
        for (int tt = 0; tt < 4; ++tt) {
            const int rowP = 64 * (r16 & 3) + 16 * w + 4 * tt + (r16 >> 2);
            #pragma unroll
            for (int ks = 0; ks < 2; ++ks) {
                a0[tt][ks]     = cvt8(W_hh0 + rowP * HID + ks * 32 + g4 * 8);
                a1[tt][ks]     = cvt8(W_ih1 + rowP * HID + ks * 32 + g4 * 8);
                a1[tt][2 + ks] = cvt8(W_hh1 + rowP * HID + ks * 32 + g4 * 8);
            }
        }
    }

    // ---------------- cell constants (cell waves): unit l -------------------
    float bias0v[4], bias1v[4], wih0v[4];
    if (isCell) {
        #pragma unroll
        for (int r = 0; r < 4; ++r) {
            const int grow = 64 * r + l;
            bias0v[r] = b_ih0[grow] + b_hh0[grow];
            bias1v[r] = b_ih1[grow] + b_hh1[grow];
            wih0v[r]  = W_ih0[grow];
        }
    }

    // ---------------- init ----------------
    if (tid < 320) {   // 320 ints = 2*NB*80 halves per array
        ((int*)h1f)[tid] = 0; ((int*)h2f16)[tid] = 0;
    }
    const size_t xbase = (size_t)(B0 + cb) * SEQT;
    float xc = 0.0f, xcn = 0.0f;
    if (isCell) xc = x[xbase + l];     // chunk for t = 0..63 (lane = t offset)
    float c1 = 0.0f, c2 = 0.0f;        // both cells live on the cell wave
    __syncthreads();
    if (isCell) __builtin_amdgcn_s_setprio(1);   // cell = serial critical path

    const f4 z4 = {0.f, 0.f, 0.f, 0.f};

    // one iteration; P = t&1 compile-time at every call site
    auto step = [&](int t_, int P,
                    bool L0A, bool G1A, bool C0A, bool C1A, bool FIN) {
        const int RB1 = P ^ 1;         // buf of h1(t-1)
        f4 p0, p1, p2, p3;             // L1 chains (p0,p1 live A -> B)

        // ================= Phase A =================
        if (isCell) {
            if (((t_ & 63) == 0) && (t_ + 64 < SEQT))
                xcn = x[xbase + t_ + 64 + l];
            if (C1A) {                 // cell1(t-2), batch cb, unit l
                f4 g = *(const f4*)&G1[cb][4 * l];       // one b128: 4 gates
                float iv = sigm(g[0] + bias1v[0]);
                float fv = sigm(g[1] + bias1v[1]);
                float gv = tanh_fast(g[2] + bias1v[2]);
                float ov = sigm(g[3] + bias1v[3]);
                c2 = fmaf(fv, c2, iv * gv);
                float hv = ov * tanh_fast(c2);
                _Float16 hh = (_Float16)hv;
                h2f16[P][cb][l] = hh;  // h2(t-2) -> buf (t-2)&1 == P
                if (FIN) h2fin[cb][l] = (float)hh;
            }
        } else {
            h8 b1h0, b1h1;
            if (L0A || G1A) {
                b1h0 = *(const h8*)&h1f[RB1][cc][g4 * 8];
                b1h1 = *(const h8*)&h1f[RB1][cc][32 + g4 * 8];
            }
            __builtin_amdgcn_s_setprio(1);
            if (L0A) {                 // L0(t): 4 chains depth 2 -> G0
                f4 e0 = MFMA16(a0[0][0], b1h0, z4);
                f4 e1 = MFMA16(a0[1][0], b1h0, z4);
                f4 e2 = MFMA16(a0[2][0], b1h0, z4);
                f4 e3 = MFMA16(a0[3][0], b1h0, z4);
                e0 = MFMA16(a0[0][1], b1h1, e0);
                e1 = MFMA16(a0[1][1], b1h1, e1);
                e2 = MFMA16(a0[2][1], b1h1, e2);
                e3 = MFMA16(a0[3][1], b1h1, e3);
                if (r16 < NB) {        // unit-major: f4 = 4 gates of unit u
                    const int u = 16 * w + g4;           // + 4*tt below
                    *(f4*)&G0[r16][4 * (u + 0)]  = e0;
                    *(f4*)&G0[r16][4 * (u + 4)]  = e1;
                    *(f4*)&G0[r16][4 * (u + 8)]  = e2;
                    *(f4*)&G0[r16][4 * (u + 12)] = e3;
                }
            }
            if (G1A) {                 // L1(t-1) h1-half, tiles 0,1 only
                p0 = MFMA16(a1[0][0], b1h0, z4);
                p1 = MFMA16(a1[1][0], b1h0, z4);
                p0 = MFMA16(a1[0][1], b1h1, p0);
                p1 = MFMA16(a1[1][1], b1h1, p1);
            }
            __builtin_amdgcn_s_setprio(0);
        }
        __syncthreads();               // G0(t), h2(t-2) visible

        // ================= Phase B =================
        if (isCell) {
            if (C0A) {                 // cell0(t), batch cb, unit l
                f4 g = *(const f4*)&G0[cb][4 * l];       // one b128: 4 gates
                const float xt = __shfl(xc, t_ & 63);
                float iv = sigm(g[0] + fmaf(xt, wih0v[0], bias0v[0]));
                float fv = sigm(g[1] + fmaf(xt, wih0v[1], bias0v[1]));
                float gv = tanh_fast(g[2] + fmaf(xt, wih0v[2], bias0v[2]));
                float ov = sigm(g[3] + fmaf(xt, wih0v[3], bias0v[3]));
                c1 = fmaf(fv, c1, iv * gv);
                float hv = ov * tanh_fast(c1);
                h1f[P][cb][l] = (_Float16)hv;   // h1(t) -> buf t&1 == P
            }
            if ((t_ & 63) == 63) xc = xcn;
        } else {
            if (G1A) {                 // L1(t-1): tiles 2,3 h1-half + all h2
                h8 b1h0 = *(const h8*)&h1f[RB1][cc][g4 * 8];      // still valid
                h8 b1h1 = *(const h8*)&h1f[RB1][cc][32 + g4 * 8];
                h8 b2h0 = *(const h8*)&h2f16[P][cc][g4 * 8];
                h8 b2h1 = *(const h8*)&h2f16[P][cc][32 + g4 * 8];
                __builtin_amdgcn_s_setprio(1);
                p2 = MFMA16(a1[2][0], b1h0, z4);
                p3 = MFMA16(a1[3][0], b1h0, z4);
                p2 = MFMA16(a1[2][1], b1h1, p2);
                p3 = MFMA16(a1[3][1], b1h1, p3);
                p0 = MFMA16(a1[0][2], b2h0, p0);
                p1 = MFMA16(a1[1][2], b2h0, p1);
                p2 = MFMA16(a1[2][2], b2h0, p2);
                p3 = MFMA16(a1[3][2], b2h0, p3);
                p0 = MFMA16(a1[0][3], b2h1, p0);
                p1 = MFMA16(a1[1][3], b2h1, p1);
                p2 = MFMA16(a1[2][3], b2h1, p2);
                p3 = MFMA16(a1[3][3], b2h1, p3);
                __builtin_amdgcn_s_setprio(0);
                if (r16 < NB) {
                    const int u = 16 * w + g4;
                    *(f4*)&G1[r16][4 * (u + 0)]  = p0;
                    *(f4*)&G1[r16][4 * (u + 4)]  = p1;
                    *(f4*)&G1[r16][4 * (u + 8)]  = p2;
                    *(f4*)&G1[r16][4 * (u + 12)] = p3;
                }
            }
        }
        __syncthreads();               // G1(t-1), h1(t) visible
    };

    //            t    P  L0A    G1A    C0A    C1A    FIN
    step(        0,    0, true,  false, true,  false, false);
    step(        1,    1, true,  true,  true,  false, false);
    #pragma unroll 1
    for (int t = 2; t < SEQT; t += 2) {
        step(t,      0, true,  true,  true,  true,  false);
        step(t + 1,  1, true,  true,  true,  true,  false);
    }
    step(     SEQT,    0, false, true,  false, true,  false);
    step( SEQT + 1,    1, false, false, false, true,  true );

    // ---------------- FC head: waves 0-3 -> batch w ----------------
    if (w < 4) {
        float z = 0.0f;
        if (l < 32) {
            float acc = fc1_b[l];
            const f4* hvp = (const f4*)h2fin[w];
            const f4* wvp = (const f4*)(fc1_w + l * HID);
            #pragma unroll
            for (int q = 0; q < 16; ++q) {
                f4 hq = hvp[q], wk = wvp[q];
                acc = fmaf(hq[0], wk[0], acc); acc = fmaf(hq[1], wk[1], acc);
                acc = fmaf(hq[2], wk[2], acc); acc = fmaf(hq[3], wk[3], acc);
            }
            z = fmaxf(acc, 0.0f) * fc2_w[l];
        }
        #pragma unroll
        for (int off = 32; off > 0; off >>= 1) z += __shfl_xor(z, off);
        if (l == 0) out[B0 + w] = z + fc2_b[0];
    }
}

extern "C" void kernel_launch(void* const* d_in, const int* in_sizes, int n_in,
                              void* d_out, int out_size, void* d_ws, size_t ws_size,
                              hipStream_t stream) {
    const float* x     = (const float*)d_in[0];
    const float* W_ih0 = (const float*)d_in[1];
    const float* W_hh0 = (const float*)d_in[2];
    const float* b_ih0 = (const float*)d_in[3];
    const float* b_hh0 = (const float*)d_in[4];
    const float* W_ih1 = (const float*)d_in[5];
    const float* W_hh1 = (const float*)d_in[6];
    const float* b_ih1 = (const float*)d_in[7];
    const float* b_hh1 = (const float*)d_in[8];
    const float* fc1_w = (const float*)d_in[9];
    const float* fc1_b = (const float*)d_in[10];
    const float* fc2_w = (const float*)d_in[11];
    const float* fc2_b = (const float*)d_in[12];
    float* out = (float*)d_out;

    const int batch = in_sizes[0] / SEQT;   // 1024
    const int nblk  = batch / NB;           // 256 blocks, 1 per CU
    dim3 grid(nblk), block(512);
    hipLaunchKernelGGL(lstm2_v19, grid, block, 0, stream,
                       x, W_ih0, W_hh0, b_ih0, b_hh0,
                       W_ih1, W_hh1, b_ih1, b_hh1,
                       fc1_w, fc1_b, fc2_w, fc2_b, out, nblk);
}